// Round 16
// baseline (666.684 us; speedup 1.0000x reference)
//
#include <hip/hip_runtime.h>
#include <math.h>

#define D 768
#define DF4 192      // D/4
#define SEQ 128
#define TN 192       // docs per block tile (48 per wave, wave-private)
#define DPW 48
#define NBK 64       // top-k segments per row
#define TOPK 10
#define NSEG 8       // rescore segments per row
#define CPS 80       // candidates per rescore segment (640/8)

typedef __attribute__((ext_vector_type(8))) short bh8;    // 8 bf16 = 4 VGPR
typedef __attribute__((ext_vector_type(4))) float f32x4;

#define AS1 __attribute__((address_space(1)))
#define AS3 __attribute__((address_space(3)))

__device__ __forceinline__ unsigned short f2bf(float f) {  // RTNE f32->bf16
  unsigned u = __float_as_uint(f);
  return (unsigned short)((u + 0x7FFF + ((u >> 16) & 1)) >> 16);
}

// ---------------- K1: mean over sequence ----------------
__global__ __launch_bounds__(256) void k_mean(const float* __restrict__ q,
                                              float* __restrict__ qmean) {
  int d = blockIdx.x * 256 + threadIdx.x;
  int b = blockIdx.y;
  if (d >= D) return;
  const float* p = q + (long)b * SEQ * D + d;
  float s = 0.f;
  #pragma unroll 8
  for (int i = 0; i < SEQ; ++i) s += p[(long)i * D];
  qmean[b * D + d] = s * (1.0f / SEQ);
}

// ---------------- K2: projection + bias + L2 normalize ----------------
// Emits bf16 qnorm PRE-SWIZZLED (slot' = slot ^ (row&7)) for k_scores' A-LDS.
__global__ __launch_bounds__(256) void k_proj(const float* __restrict__ qmean,
                                              const float* __restrict__ W,
                                              const float* __restrict__ bias,
                                              float* __restrict__ qnorm,
                                              unsigned short* __restrict__ qbf) {
  __shared__ float4 qm[DF4];
  __shared__ float red[256];
  int b = blockIdx.x, t = threadIdx.x;
  for (int i = t; i < DF4; i += 256) qm[i] = ((const float4*)qmean)[b * DF4 + i];
  __syncthreads();
  float myout[3];
  #pragma unroll
  for (int i = 0; i < 3; ++i) {
    int j = t + i * 256;
    const float4* wr = (const float4*)W + (long)j * DF4;
    float a0 = 0.f, a1 = 0.f, a2 = 0.f, a3 = 0.f;
    for (int kk = 0; kk < DF4; ++kk) {
      float4 w = wr[kk]; float4 qv = qm[kk];
      a0 = fmaf(w.x, qv.x, a0); a1 = fmaf(w.y, qv.y, a1);
      a2 = fmaf(w.z, qv.z, a2); a3 = fmaf(w.w, qv.w, a3);
    }
    myout[i] = (a0 + a1) + (a2 + a3) + bias[j];
  }
  float ss = myout[0]*myout[0] + myout[1]*myout[1] + myout[2]*myout[2];
  red[t] = ss;
  __syncthreads();
  for (int h = 128; h > 0; h >>= 1) {
    if (t < h) red[t] += red[t + h];
    __syncthreads();
  }
  float rn = 1.0f / fmaxf(sqrtf(red[0]), 1e-12f);
  #pragma unroll
  for (int i = 0; i < 3; ++i) {
    int j = t + i * 256;
    float v = myout[i] * rn;
    qnorm[b * D + j] = v;
    int slot = j >> 3;
    qbf[b * D + ((slot ^ (b & 7)) << 3) + (j & 7)] = f2bf(v);
  }
}

// ---------------- K3: cosine scores via MFMA bf16, full-page staging --------
// r13/r14/r15 all landed at 526-527us across 3 schedule variants -> binder is
// the ACCESS PATTERN: 24 x 128B pieces per 3072B doc row = 8 DRAM page
// activations per 1KB page delivering 128B each (~3.4 TB/s effective).
// r16: granule = 8 K-steps; one wave-inst = ONE 1KB contiguous doc segment
// (64 lanes x 16B) -> 1 activation/page. TN=192: B = 192x512B bf16 = 96KB,
// A = 48KB, norms 768B -> 145KB LDS, 1 block/CU.
// KEY: wave w stages AND consumes docs [w*48,w*48+48) -> B and norms are
// WAVE-PRIVATE -> no in-loop barriers (DS pipe is in-order per wave); one
// barrier total for the cross-wave A tile. Staging: 6 batches x 8 doc-rows,
// 2-deep rbA/rbB register pipeline (16KB in flight/wave), f32->bf16 cvt +
// ssq shfl-reduce absorbed under the HBM-bound stage phase. A/B/C MFMA lane
// mappings identical to the r12-r15-proven kernel.
__global__ __launch_bounds__(256) __attribute__((amdgpu_waves_per_eu(1)))
void k_scores(const float* __restrict__ docs,
              const unsigned short* __restrict__ qbf,
              float* __restrict__ outS, int N) {
  __shared__ f32x4 smem4[148224 / 16];  // A 48K | B 96K | nL 768B
  char* sm = (char*)smem4;
  char* smB = sm + 49152;
  float* nL = (float*)(sm + 147456);
  const int t = threadIdx.x, l = t & 63, w = t >> 6;
  const int wloc = w * DPW;
  const long tile0 = (long)blockIdx.x * TN;
  const char* docsb = (const char*)docs;

  // --- A DMA: 48 KB linear (qbf already swizzled) ---
  {
    const char* qb = (const char*)qbf;
    #pragma unroll
    for (int i = 0; i < 12; ++i) {
      int off = __builtin_amdgcn_readfirstlane((w * 12 + i) << 10);
      __builtin_amdgcn_global_load_lds((const AS1 void*)(qb + off + l * 16),
                                       (AS3 void*)(sm + off), 16, 0, 0);
    }
  }

  f32x4 rbA[8], rbB[8];
  f32x4 acc[2][3];
  #pragma unroll
  for (int m = 0; m < 2; ++m)
    #pragma unroll
    for (int n = 0; n < 3; ++n) acc[m][n] = (f32x4){0.f, 0.f, 0.f, 0.f};

// one wave-inst per doc row: 64 lanes x 16B = 1 KB CONTIGUOUS
#define LOADB(RB, g, bb) do {                                                \
    _Pragma("unroll")                                                        \
    for (int j_ = 0; j_ < 8; ++j_) {                                         \
      int doc_ = (int)tile0 + wloc + (bb) * 8 + j_;                          \
      if (doc_ > N - 1) doc_ = N - 1;                                        \
      RB[j_] = *(const f32x4*)(docsb + ((unsigned)doc_ * 3072u +             \
                               ((unsigned)(g) << 10) + (unsigned)(l * 16))); \
    }                                                                        \
  } while (0)

#define CVTW(g, RB, bb) do {                                                 \
    _Pragma("unroll")                                                        \
    for (int j_ = 0; j_ < 8; ++j_) {                                         \
      int dl_ = wloc + (bb) * 8 + j_;                                        \
      f32x4 v_ = RB[j_];                                                     \
      float s_ = v_.x * v_.x;                                                \
      s_ = fmaf(v_.y, v_.y, s_);                                             \
      s_ = fmaf(v_.z, v_.z, s_);                                             \
      s_ = fmaf(v_.w, v_.w, s_);                                             \
      s_ += __shfl_xor(s_, 1);  s_ += __shfl_xor(s_, 2);                     \
      s_ += __shfl_xor(s_, 4);  s_ += __shfl_xor(s_, 8);                     \
      s_ += __shfl_xor(s_, 16); s_ += __shfl_xor(s_, 32);                    \
      ushort4 u_;                                                            \
      u_.x = f2bf(v_.x); u_.y = f2bf(v_.y);                                  \
      u_.z = f2bf(v_.z); u_.w = f2bf(v_.w);                                  \
      *(ushort4*)(smB + dl_ * 512 +                                          \
                  ((unsigned)(l * 8) ^ (unsigned)((dl_ & 7) << 4))) = u_;    \
      if (l == 0) nL[dl_] = ((g) == 0) ? s_ : (nL[dl_] + s_);                \
    }                                                                        \
  } while (0)

#define STAGE(g) do {                                                        \
    LOADB(rbA, g, 0); LOADB(rbB, g, 1);                                      \
    CVTW(g, rbA, 0);  LOADB(rbA, g, 2);                                      \
    CVTW(g, rbB, 1);  LOADB(rbB, g, 3);                                      \
    CVTW(g, rbA, 2);  LOADB(rbA, g, 4);                                      \
    CVTW(g, rbB, 3);  LOADB(rbB, g, 5);                                      \
    CVTW(g, rbA, 4);  CVTW(g, rbB, 5);                                       \
  } while (0)

#define MFMAG(g) do {                                                        \
    _Pragma("unroll")                                                        \
    for (int cc_ = 0; cc_ < 8; ++cc_) {                                      \
      int sA0_ = ((g) * 8 + cc_) * 4 + (l >> 4);                             \
      int r0_ = (l & 15), r1_ = 16 + (l & 15);                               \
      bh8 aF0_ = *(const bh8*)(sm + r0_ * 1536 + ((sA0_ ^ (r0_ & 7)) << 4)); \
      bh8 aF1_ = *(const bh8*)(sm + r1_ * 1536 + ((sA0_ ^ (r1_ & 7)) << 4)); \
      _Pragma("unroll")                                                      \
      for (int n_ = 0; n_ < 3; ++n_) {                                       \
        int dl_ = wloc + n_ * 16 + (l & 15);                                 \
        bh8 bF_ = *(const bh8*)(smB + dl_ * 512 +                            \
                   (((unsigned)(cc_ * 64 + ((l >> 4) << 4))) ^               \
                    ((unsigned)((dl_ & 7) << 4))));                          \
        acc[0][n_] = __builtin_amdgcn_mfma_f32_16x16x32_bf16(aF0_, bF_,      \
                                                         acc[0][n_], 0,0,0); \
        acc[1][n_] = __builtin_amdgcn_mfma_f32_16x16x32_bf16(aF1_, bF_,      \
                                                         acc[1][n_], 0,0,0); \
      }                                                                      \
    }                                                                        \
  } while (0)

  STAGE(0);
  __syncthreads();   // A tile ready (B / nL are wave-private)
  MFMAG(0);
  STAGE(1);
  MFMAG(1);
  STAGE(2);
  MFMAG(2);
#undef LOADB
#undef CVTW
#undef STAGE
#undef MFMAG

  // --- epilogue: wave-private norms + C write (col=lane&15, row=(l>>4)*4+r) ---
  #pragma unroll
  for (int n = 0; n < 3; ++n) {
    int dl = wloc + n * 16 + (l & 15);
    long gd = tile0 + dl;
    if (gd < N) {
      float rn = 1.0f / fmaxf(sqrtf(nL[dl]), 1e-12f);
      #pragma unroll
      for (int m = 0; m < 2; ++m) {
        #pragma unroll
        for (int r = 0; r < 4; ++r) {
          int qrow = m * 16 + (l >> 4) * 4 + r;
          outS[(long)qrow * N + gd] = acc[m][n][r] * rn;
        }
      }
    }
  }
}

// ---------------- top-k helpers ----------------
__device__ __forceinline__ void insert10(float v, float p, float bs[10], float bi[10]) {
  bool last = (v > bs[9]) || (v == bs[9] && p < bi[9]);
  if (!last) return;
  #pragma unroll
  for (int j = 9; j >= 1; --j) {
    bool bj  = (v > bs[j])   || (v == bs[j]   && p < bi[j]);
    bool bjm = (v > bs[j-1]) || (v == bs[j-1] && p < bi[j-1]);
    float ns = bj ? (bjm ? bs[j-1] : v) : bs[j];
    float ni = bj ? (bjm ? bi[j-1] : p) : bi[j];
    bs[j] = ns; bi[j] = ni;
  }
  bool b0 = (v > bs[0]) || (v == bs[0] && p < bi[0]);
  if (b0) { bs[0] = v; bi[0] = p; }
}

// shared-LDS 256-thread top-10 merge; result in ms/mi[0]
__device__ __forceinline__ void blockmerge10(float bs[10], float bi[10],
                                             float (*ms)[10], float (*mi)[10],
                                             int t) {
  #pragma unroll
  for (int k = 0; k < 10; ++k) { ms[t][k] = bs[k]; mi[t][k] = bi[k]; }
  __syncthreads();
  for (int h = 128; h > 0; h >>= 1) {
    if (t < h) {
      float os[10], oi[10];
      int x = 0, y = 0;
      #pragma unroll
      for (int k = 0; k < 10; ++k) {
        float sx = ms[t][x], sy = ms[t + h][y];
        float ix = mi[t][x], iy = mi[t + h][y];
        bool ta = (sx > sy) || (sx == sy && ix < iy);
        os[k] = ta ? sx : sy; oi[k] = ta ? ix : iy;
        x += ta ? 1 : 0; y += ta ? 0 : 1;
      }
      #pragma unroll
      for (int k = 0; k < 10; ++k) { ms[t][k] = os[k]; mi[t][k] = oi[k]; }
    }
    __syncthreads();
  }
}

// ---------------- K4: per-(row, segment) top-10 on MFMA scores ----------------
__global__ __launch_bounds__(256) void k_topblk(const float* __restrict__ scores,
                                                float2* __restrict__ btop, int N) {
  const int row = blockIdx.y, seg = blockIdx.x, t = threadIdx.x;
  const int per = (N + NBK - 1) / NBK;
  const int s0 = seg * per;
  const int s1 = (s0 + per < N) ? (s0 + per) : N;
  const float* rp = scores + (long)row * N;
  float bs[10], bi[10];
  #pragma unroll
  for (int k = 0; k < 10; ++k) { bs[k] = -INFINITY; bi[k] = 2.0e9f; }
  for (int p = s0 + t; p < s1; p += 256) insert10(rp[p], (float)p, bs, bi);

  __shared__ float ms[256][10];
  __shared__ float mi[256][10];
  blockmerge10(bs, bi, ms, mi, t);
  if (t == 0) {
    #pragma unroll
    for (int k = 0; k < 10; ++k)
      btop[((long)row * NBK + seg) * 10 + k] = make_float2(ms[0][k], mi[0][k]);
  }
}

// ---------------- K5a: exact f32 rescore, parallel over 8 segments/row -------
__global__ __launch_bounds__(256) void k_rescore(const float* __restrict__ docs,
                                                 const float* __restrict__ qn,
                                                 const float2* __restrict__ btop,
                                                 float2* __restrict__ btop2, int N) {
  const int seg = blockIdx.x, row = blockIdx.y, t = threadIdx.x;
  __shared__ float4 qrow[DF4];
  if (t < DF4) qrow[t] = ((const float4*)qn)[row * DF4 + t];
  __syncthreads();
  float bs[10], bi[10];
  #pragma unroll
  for (int k = 0; k < 10; ++k) { bs[k] = -INFINITY; bi[k] = 2.0e9f; }
  if (t < CPS) {
    float2 c = btop[(long)row * (NBK * 10) + seg * CPS + t];
    int doc = (int)c.y;
    const float4* dp = (const float4*)docs + (long)doc * DF4;
    float a0 = 0.f, a1 = 0.f, a2 = 0.f, a3 = 0.f;
    float s0 = 0.f, s1 = 0.f, s2 = 0.f, s3 = 0.f;
    for (int kk = 0; kk < DF4; ++kk) {
      float4 d4 = dp[kk]; float4 q4 = qrow[kk];
      a0 = fmaf(q4.x, d4.x, a0); a1 = fmaf(q4.y, d4.y, a1);
      a2 = fmaf(q4.z, d4.z, a2); a3 = fmaf(q4.w, d4.w, a3);
      s0 = fmaf(d4.x, d4.x, s0); s1 = fmaf(d4.y, d4.y, s1);
      s2 = fmaf(d4.z, d4.z, s2); s3 = fmaf(d4.w, d4.w, s3);
    }
    float nrm = sqrtf((s0 + s1) + (s2 + s3));
    insert10(((a0 + a1) + (a2 + a3)) / fmaxf(nrm, 1e-12f), c.y, bs, bi);
  }
  __shared__ float ms[256][10];
  __shared__ float mi[256][10];
  blockmerge10(bs, bi, ms, mi, t);
  if (t == 0) {
    #pragma unroll
    for (int k = 0; k < 10; ++k)
      btop2[((long)row * NSEG + seg) * 10 + k] = make_float2(ms[0][k], mi[0][k]);
  }
}

// ---------------- K5b: final 80 -> 10 merge per row --------------------------
__global__ __launch_bounds__(256) void k_topfinal(const float2* __restrict__ btop2,
                                                  float* __restrict__ outIdx) {
  const int row = blockIdx.x, t = threadIdx.x;
  const int M = NSEG * 10;   // 80
  float bs[10], bi[10];
  #pragma unroll
  for (int k = 0; k < 10; ++k) { bs[k] = -INFINITY; bi[k] = 2.0e9f; }
  if (t < M) {
    float2 c = btop2[(long)row * M + t];
    insert10(c.x, c.y, bs, bi);
  }
  __shared__ float ms[256][10];
  __shared__ float mi[256][10];
  blockmerge10(bs, bi, ms, mi, t);
  if (t == 0) {
    #pragma unroll
    for (int k = 0; k < 10; ++k) outIdx[row * TOPK + k] = mi[0][k];
  }
}

extern "C" void kernel_launch(void* const* d_in, const int* in_sizes, int n_in,
                              void* d_out, int out_size, void* d_ws, size_t ws_size,
                              hipStream_t stream) {
  const float* q    = (const float*)d_in[0];   // [32,128,768]
  const float* docs = (const float*)d_in[1];   // [N,768]
  const float* W    = (const float*)d_in[2];   // [768,768]
  const float* bias = (const float*)d_in[3];   // [768]
  const int B = in_sizes[0] / (SEQ * D);       // 32
  const int N = in_sizes[1] / D;               // 500000

  float* out    = (float*)d_out;
  float* outIdx = out;                          // [B*10] indices as float
  float* outS   = out + (long)B * TOPK;         // [B][N] scores

  float* qmean = (float*)d_ws;                               // B*D f32
  float* qnorm = qmean + (long)B * D;                        // B*D f32
  unsigned short* qbf = (unsigned short*)(qnorm + (long)B * D); // B*D bf16 swz
  float2* btop  = (float2*)((char*)qbf + (long)B * D * 2);   // B*NBK*10
  float2* btop2 = btop + (long)B * NBK * 10;                 // B*NSEG*10

  dim3 g1(3, B);
  k_mean<<<g1, 256, 0, stream>>>(q, qmean);
  k_proj<<<B, 256, 0, stream>>>(qmean, W, bias, qnorm, qbf);
  int ntiles = (N + TN - 1) / TN;
  k_scores<<<ntiles, 256, 0, stream>>>(docs, qbf, outS, N);
  dim3 g4(NBK, B);
  k_topblk<<<g4, 256, 0, stream>>>(outS, btop, N);
  dim3 g5(NSEG, B);
  k_rescore<<<g5, 256, 0, stream>>>(docs, qnorm, btop, btop2, N);
  k_topfinal<<<B, 256, 0, stream>>>(btop2, outIdx);
}

// Round 17
// 534.049 us; speedup vs baseline: 1.2484x; 1.2484x over previous
//
#include <hip/hip_runtime.h>
#include <math.h>

#define D 768
#define DF4 192      // D/4
#define SEQ 128
#define TN 256       // docs per block tile (64 per wave, wave-private)
#define NBK 64       // top-k segments per row
#define TOPK 10
#define NGRAN 12     // granules; each = 2 K-steps = 256B f32 per doc
#define NSEG 8       // rescore segments per row
#define CPS 80       // candidates per rescore segment (640/8)

typedef __attribute__((ext_vector_type(8))) short bh8;    // 8 bf16 = 4 VGPR
typedef __attribute__((ext_vector_type(4))) float f32x4;

#define AS1 __attribute__((address_space(1)))
#define AS3 __attribute__((address_space(3)))

__device__ __forceinline__ unsigned short f2bf(float f) {  // RTNE f32->bf16
  unsigned u = __float_as_uint(f);
  return (unsigned short)((u + 0x7FFF + ((u >> 16) & 1)) >> 16);
}

// ---------------- K1: mean over sequence ----------------
__global__ __launch_bounds__(256) void k_mean(const float* __restrict__ q,
                                              float* __restrict__ qmean) {
  int d = blockIdx.x * 256 + threadIdx.x;
  int b = blockIdx.y;
  if (d >= D) return;
  const float* p = q + (long)b * SEQ * D + d;
  float s = 0.f;
  #pragma unroll 8
  for (int i = 0; i < SEQ; ++i) s += p[(long)i * D];
  qmean[b * D + d] = s * (1.0f / SEQ);
}

// ---------------- K2: projection + bias + L2 normalize ----------------
// Emits bf16 qnorm PRE-SWIZZLED (slot' = slot ^ (row&7)) for k_scores' A-LDS.
__global__ __launch_bounds__(256) void k_proj(const float* __restrict__ qmean,
                                              const float* __restrict__ W,
                                              const float* __restrict__ bias,
                                              float* __restrict__ qnorm,
                                              unsigned short* __restrict__ qbf) {
  __shared__ float4 qm[DF4];
  __shared__ float red[256];
  int b = blockIdx.x, t = threadIdx.x;
  for (int i = t; i < DF4; i += 256) qm[i] = ((const float4*)qmean)[b * DF4 + i];
  __syncthreads();
  float myout[3];
  #pragma unroll
  for (int i = 0; i < 3; ++i) {
    int j = t + i * 256;
    const float4* wr = (const float4*)W + (long)j * DF4;
    float a0 = 0.f, a1 = 0.f, a2 = 0.f, a3 = 0.f;
    for (int kk = 0; kk < DF4; ++kk) {
      float4 w = wr[kk]; float4 qv = qm[kk];
      a0 = fmaf(w.x, qv.x, a0); a1 = fmaf(w.y, qv.y, a1);
      a2 = fmaf(w.z, qv.z, a2); a3 = fmaf(w.w, qv.w, a3);
    }
    myout[i] = (a0 + a1) + (a2 + a3) + bias[j];
  }
  float ss = myout[0]*myout[0] + myout[1]*myout[1] + myout[2]*myout[2];
  red[t] = ss;
  __syncthreads();
  for (int h = 128; h > 0; h >>= 1) {
    if (t < h) red[t] += red[t + h];
    __syncthreads();
  }
  float rn = 1.0f / fmaxf(sqrtf(red[0]), 1e-12f);
  #pragma unroll
  for (int i = 0; i < 3; ++i) {
    int j = t + i * 256;
    float v = myout[i] * rn;
    qnorm[b * D + j] = v;
    int slot = j >> 3;
    qbf[b * D + ((slot ^ (b & 7)) << 3) + (j & 7)] = f2bf(v);
  }
}

// ---------------- K3: cosine scores via MFMA bf16 -----------------------
// r17. r13-r15 (527us) were schedule-invariant; r16 isolated nothing
// (contiguity bundled with occupancy collapse + shfl storm). r17 tests
// contiguity cleanly:
//  - granule = 2 K-steps: one wave-inst = 4 docs x 256B CONTIGUOUS (2x
//    r13's request size, half the request count).
//  - B single-buffer 32KB (wave-private rows; per-wave in-order DS makes
//    read-then-overwrite safe — r16-validated) + A 48KB = 80KB exactly
//    -> 2 blocks/CU, ZERO in-loop barriers; waves self-pace.
//  - doc norms on the MFMA pipe: accN[n] = mfma(bF, bF, accN[n]) — A/B
//    frags of 16x16x32 are layout-symmetric so bF-as-A = B^T; diagonal of
//    B^T B accumulates |doc|^2 over all K. Kills r16's 900-shfl storm.
//    Norms are bf16-quantized: ~1e-4 RELATIVE score error (rescore is
//    exact f32; candidate margin unaffected).
//  - T5 setprio around MFMA cluster (self-paced waves = role diversity).
__global__ __launch_bounds__(256) __attribute__((amdgpu_waves_per_eu(2)))
void k_scores(const float* __restrict__ docs,
              const unsigned short* __restrict__ qbf,
              float* __restrict__ outS, int N) {
  __shared__ f32x4 smem4[81920 / 16];   // A [0,48K) | B [48K,80K)
  char* sm = (char*)smem4;
  char* smB = sm + 49152;
  const int t = threadIdx.x, l = t & 63, w = t >> 6;
  const int wloc = w * 64;              // wave's private doc range
  const long tile0 = (long)blockIdx.x * TN;
  const char* docsb = (const char*)docs;

  // --- A DMA: 48 KB linear (qbf already swizzled) ---
  {
    const char* qb = (const char*)qbf;
    #pragma unroll
    for (int i = 0; i < 12; ++i) {
      int off = __builtin_amdgcn_readfirstlane((w * 12 + i) << 10);
      __builtin_amdgcn_global_load_lds((const AS1 void*)(qb + off + l * 16),
                                       (AS3 void*)(sm + off), 16, 0, 0);
    }
  }

  f32x4 rbA[8], rbB[8];
  f32x4 acc[2][4];
  f32x4 accN[4];
  #pragma unroll
  for (int m = 0; m < 2; ++m)
    #pragma unroll
    for (int n = 0; n < 4; ++n) acc[m][n] = (f32x4){0.f, 0.f, 0.f, 0.f};
  #pragma unroll
  for (int n = 0; n < 4; ++n) accN[n] = (f32x4){0.f, 0.f, 0.f, 0.f};

// one wave-inst = 4 docs x 256B contiguous (16 lanes per doc)
#define LOADB(RB, g, bb) do {                                                \
    _Pragma("unroll")                                                        \
    for (int j_ = 0; j_ < 8; ++j_) {                                         \
      int doc_ = (int)tile0 + wloc + (bb) * 32 + j_ * 4 + (l >> 4);          \
      if (doc_ > N - 1) doc_ = N - 1;                                        \
      RB[j_] = *(const f32x4*)(docsb + ((unsigned)doc_ * 3072u +             \
                 ((unsigned)(g) << 8) + (unsigned)((l & 15) * 16)));         \
    }                                                                        \
  } while (0)

// cvt f32x4 -> 8B bf16, write into wave-private B row with XOR swizzle.
// 16-lane phase writes one doc's 128B (permuted) -> conflict-free.
#define CVTW(RB, bb) do {                                                    \
    _Pragma("unroll")                                                        \
    for (int j_ = 0; j_ < 8; ++j_) {                                         \
      int dl_ = wloc + (bb) * 32 + j_ * 4 + (l >> 4);                        \
      f32x4 v_ = RB[j_];                                                     \
      ushort4 u_;                                                            \
      u_.x = f2bf(v_.x); u_.y = f2bf(v_.y);                                  \
      u_.z = f2bf(v_.z); u_.w = f2bf(v_.w);                                  \
      int s16_ = ((l & 15) >> 1) ^ (dl_ & 7);                                \
      *(ushort4*)(smB + dl_ * 128 + (s16_ << 4) + ((l & 1) << 3)) = u_;      \
    }                                                                        \
  } while (0)

// granule g = K-steps 2g, 2g+1. Score MFMAs + norm MFMA (bF as both ops).
#define MFMAG(g) do {                                                        \
    __builtin_amdgcn_s_setprio(1);                                           \
    _Pragma("unroll")                                                        \
    for (int cc_ = 0; cc_ < 2; ++cc_) {                                      \
      int sA0_ = ((g) * 2 + cc_) * 4 + (l >> 4);                             \
      int r0_ = (l & 15), r1_ = 16 + (l & 15);                               \
      bh8 aF0_ = *(const bh8*)(sm + r0_ * 1536 + ((sA0_ ^ (r0_ & 7)) << 4)); \
      bh8 aF1_ = *(const bh8*)(sm + r1_ * 1536 + ((sA0_ ^ (r1_ & 7)) << 4)); \
      _Pragma("unroll")                                                      \
      for (int n_ = 0; n_ < 4; ++n_) {                                       \
        int dl_ = wloc + n_ * 16 + (l & 15);                                 \
        bh8 bF_ = *(const bh8*)(smB + dl_ * 128 +                            \
                   (((cc_ * 4 + (l >> 4)) ^ (dl_ & 7)) << 4));               \
        acc[0][n_] = __builtin_amdgcn_mfma_f32_16x16x32_bf16(aF0_, bF_,      \
                                                         acc[0][n_], 0,0,0); \
        acc[1][n_] = __builtin_amdgcn_mfma_f32_16x16x32_bf16(aF1_, bF_,      \
                                                         acc[1][n_], 0,0,0); \
        accN[n_]   = __builtin_amdgcn_mfma_f32_16x16x32_bf16(bF_, bF_,       \
                                                         accN[n_],   0,0,0); \
      }                                                                      \
    }                                                                        \
    __builtin_amdgcn_s_setprio(0);                                           \
  } while (0)

  // prologue
  LOADB(rbA, 0, 0);
  LOADB(rbB, 0, 1);
  __syncthreads();          // A tile ready (B is wave-private)
  CVTW(rbA, 0);
  CVTW(rbB, 1);

  #pragma unroll 1
  for (int g = 0; g < NGRAN; ++g) {
    if (g + 1 < NGRAN) {    // issue next granule's loads before compute
      LOADB(rbA, g + 1, 0);
      LOADB(rbB, g + 1, 1);
    }
    MFMAG(g);               // reads B (this wave's rows)
    if (g + 1 < NGRAN) {    // overwrite same rows: per-wave in-order DS
      CVTW(rbA, 0);
      CVTW(rbB, 1);
    }
  }
#undef LOADB
#undef CVTW
#undef MFMAG

  // --- norms from accN diagonals -> wave-private LDS (B area, now dead) ---
  float* nrm = (float*)(smB + w * 8192);
  if ((l >> 4) == ((l & 15) >> 2)) {
    #pragma unroll
    for (int n = 0; n < 4; ++n) nrm[n * 16 + (l & 15)] = accN[n][(l & 15) & 3];
  }
  // same-wave in-order DS: reads below see the writes above
  #pragma unroll
  for (int n = 0; n < 4; ++n) {
    int dl = wloc + n * 16 + (l & 15);
    long gd = tile0 + dl;
    if (gd < N) {
      float rn = 1.0f / fmaxf(sqrtf(nrm[n * 16 + (l & 15)]), 1e-12f);
      #pragma unroll
      for (int m = 0; m < 2; ++m) {
        #pragma unroll
        for (int r = 0; r < 4; ++r) {
          int qrow = m * 16 + (l >> 4) * 4 + r;
          outS[(long)qrow * N + gd] = acc[m][n][r] * rn;
        }
      }
    }
  }
}

// ---------------- top-k helpers ----------------
__device__ __forceinline__ void insert10(float v, float p, float bs[10], float bi[10]) {
  bool last = (v > bs[9]) || (v == bs[9] && p < bi[9]);
  if (!last) return;
  #pragma unroll
  for (int j = 9; j >= 1; --j) {
    bool bj  = (v > bs[j])   || (v == bs[j]   && p < bi[j]);
    bool bjm = (v > bs[j-1]) || (v == bs[j-1] && p < bi[j-1]);
    float ns = bj ? (bjm ? bs[j-1] : v) : bs[j];
    float ni = bj ? (bjm ? bi[j-1] : p) : bi[j];
    bs[j] = ns; bi[j] = ni;
  }
  bool b0 = (v > bs[0]) || (v == bs[0] && p < bi[0]);
  if (b0) { bs[0] = v; bi[0] = p; }
}

// shared-LDS 256-thread top-10 merge; result in ms/mi[0]
__device__ __forceinline__ void blockmerge10(float bs[10], float bi[10],
                                             float (*ms)[10], float (*mi)[10],
                                             int t) {
  #pragma unroll
  for (int k = 0; k < 10; ++k) { ms[t][k] = bs[k]; mi[t][k] = bi[k]; }
  __syncthreads();
  for (int h = 128; h > 0; h >>= 1) {
    if (t < h) {
      float os[10], oi[10];
      int x = 0, y = 0;
      #pragma unroll
      for (int k = 0; k < 10; ++k) {
        float sx = ms[t][x], sy = ms[t + h][y];
        float ix = mi[t][x], iy = mi[t + h][y];
        bool ta = (sx > sy) || (sx == sy && ix < iy);
        os[k] = ta ? sx : sy; oi[k] = ta ? ix : iy;
        x += ta ? 1 : 0; y += ta ? 0 : 1;
      }
      #pragma unroll
      for (int k = 0; k < 10; ++k) { ms[t][k] = os[k]; mi[t][k] = oi[k]; }
    }
    __syncthreads();
  }
}

// ---------------- K4: per-(row, segment) top-10 on MFMA scores ----------------
__global__ __launch_bounds__(256) void k_topblk(const float* __restrict__ scores,
                                                float2* __restrict__ btop, int N) {
  const int row = blockIdx.y, seg = blockIdx.x, t = threadIdx.x;
  const int per = (N + NBK - 1) / NBK;
  const int s0 = seg * per;
  const int s1 = (s0 + per < N) ? (s0 + per) : N;
  const float* rp = scores + (long)row * N;
  float bs[10], bi[10];
  #pragma unroll
  for (int k = 0; k < 10; ++k) { bs[k] = -INFINITY; bi[k] = 2.0e9f; }
  for (int p = s0 + t; p < s1; p += 256) insert10(rp[p], (float)p, bs, bi);

  __shared__ float ms[256][10];
  __shared__ float mi[256][10];
  blockmerge10(bs, bi, ms, mi, t);
  if (t == 0) {
    #pragma unroll
    for (int k = 0; k < 10; ++k)
      btop[((long)row * NBK + seg) * 10 + k] = make_float2(ms[0][k], mi[0][k]);
  }
}

// ---------------- K5a: exact f32 rescore, parallel over 8 segments/row -------
__global__ __launch_bounds__(256) void k_rescore(const float* __restrict__ docs,
                                                 const float* __restrict__ qn,
                                                 const float2* __restrict__ btop,
                                                 float2* __restrict__ btop2, int N) {
  const int seg = blockIdx.x, row = blockIdx.y, t = threadIdx.x;
  __shared__ float4 qrow[DF4];
  if (t < DF4) qrow[t] = ((const float4*)qn)[row * DF4 + t];
  __syncthreads();
  float bs[10], bi[10];
  #pragma unroll
  for (int k = 0; k < 10; ++k) { bs[k] = -INFINITY; bi[k] = 2.0e9f; }
  if (t < CPS) {
    float2 c = btop[(long)row * (NBK * 10) + seg * CPS + t];
    int doc = (int)c.y;
    const float4* dp = (const float4*)docs + (long)doc * DF4;
    float a0 = 0.f, a1 = 0.f, a2 = 0.f, a3 = 0.f;
    float s0 = 0.f, s1 = 0.f, s2 = 0.f, s3 = 0.f;
    for (int kk = 0; kk < DF4; ++kk) {
      float4 d4 = dp[kk]; float4 q4 = qrow[kk];
      a0 = fmaf(q4.x, d4.x, a0); a1 = fmaf(q4.y, d4.y, a1);
      a2 = fmaf(q4.z, d4.z, a2); a3 = fmaf(q4.w, d4.w, a3);
      s0 = fmaf(d4.x, d4.x, s0); s1 = fmaf(d4.y, d4.y, s1);
      s2 = fmaf(d4.z, d4.z, s2); s3 = fmaf(d4.w, d4.w, s3);
    }
    float nrm = sqrtf((s0 + s1) + (s2 + s3));
    insert10(((a0 + a1) + (a2 + a3)) / fmaxf(nrm, 1e-12f), c.y, bs, bi);
  }
  __shared__ float ms[256][10];
  __shared__ float mi[256][10];
  blockmerge10(bs, bi, ms, mi, t);
  if (t == 0) {
    #pragma unroll
    for (int k = 0; k < 10; ++k)
      btop2[((long)row * NSEG + seg) * 10 + k] = make_float2(ms[0][k], mi[0][k]);
  }
}

// ---------------- K5b: final 80 -> 10 merge per row --------------------------
__global__ __launch_bounds__(256) void k_topfinal(const float2* __restrict__ btop2,
                                                  float* __restrict__ outIdx) {
  const int row = blockIdx.x, t = threadIdx.x;
  const int M = NSEG * 10;   // 80
  float bs[10], bi[10];
  #pragma unroll
  for (int k = 0; k < 10; ++k) { bs[k] = -INFINITY; bi[k] = 2.0e9f; }
  if (t < M) {
    float2 c = btop2[(long)row * M + t];
    insert10(c.x, c.y, bs, bi);
  }
  __shared__ float ms[256][10];
  __shared__ float mi[256][10];
  blockmerge10(bs, bi, ms, mi, t);
  if (t == 0) {
    #pragma unroll
    for (int k = 0; k < 10; ++k) outIdx[row * TOPK + k] = mi[0][k];
  }
}

extern "C" void kernel_launch(void* const* d_in, const int* in_sizes, int n_in,
                              void* d_out, int out_size, void* d_ws, size_t ws_size,
                              hipStream_t stream) {
  const float* q    = (const float*)d_in[0];   // [32,128,768]
  const float* docs = (const float*)d_in[1];   // [N,768]
  const float* W    = (const float*)d_in[2];   // [768,768]
  const float* bias = (const float*)d_in[3];   // [768]
  const int B = in_sizes[0] / (SEQ * D);       // 32
  const int N = in_sizes[1] / D;               // 500000

  float* out    = (float*)d_out;
  float* outIdx = out;                          // [B*10] indices as float
  float* outS   = out + (long)B * TOPK;         // [B][N] scores

  float* qmean = (float*)d_ws;                               // B*D f32
  float* qnorm = qmean + (long)B * D;                        // B*D f32
  unsigned short* qbf = (unsigned short*)(qnorm + (long)B * D); // B*D bf16 swz
  float2* btop  = (float2*)((char*)qbf + (long)B * D * 2);   // B*NBK*10
  float2* btop2 = btop + (long)B * NBK * 10;                 // B*NSEG*10

  dim3 g1(3, B);
  k_mean<<<g1, 256, 0, stream>>>(q, qmean);
  k_proj<<<B, 256, 0, stream>>>(qmean, W, bias, qnorm, qbf);
  int ntiles = (N + TN - 1) / TN;
  k_scores<<<ntiles, 256, 0, stream>>>(docs, qbf, outS, N);
  dim3 g4(NBK, B);
  k_topblk<<<g4, 256, 0, stream>>>(outS, btop, N);
  dim3 g5(NSEG, B);
  k_rescore<<<g5, 256, 0, stream>>>(docs, qnorm, btop, btop2, N);
  k_topfinal<<<B, 256, 0, stream>>>(btop2, outIdx);
}